// Round 1
// baseline (1334.543 us; speedup 1.0000x reference)
//
#include <hip/hip_runtime.h>
#include <stdint.h>

#define BB 4
#define SS 2048
#define DD 1024
#define HH 16
#define HDD 64
#define MTOT (BB*SS)      // 8192
#define NQKV (3*DD)       // 3072

typedef __bf16 bf16x8 __attribute__((ext_vector_type(8)));
typedef float  f32x4  __attribute__((ext_vector_type(4)));
typedef unsigned short u16;
typedef u16 u16x8 __attribute__((ext_vector_type(8)));
typedef u16 u16x4 __attribute__((ext_vector_type(4)));

typedef const __attribute__((address_space(1))) void* gptr_t;
typedef __attribute__((address_space(3))) void* lptr_t;

__device__ __forceinline__ u16 f2bf(float f) {
    uint32_t u = __builtin_bit_cast(uint32_t, f);
    u += 0x7FFFu + ((u >> 16) & 1u);   // RNE
    return (u16)(u >> 16);
}
__device__ __forceinline__ float bf2f(u16 v) {
    uint32_t u = ((uint32_t)v) << 16;
    return __builtin_bit_cast(float, u);
}

// ---------------- fp32 -> bf16 convert (vectorized) ----------------
__global__ __launch_bounds__(256) void cvt_f32_bf16(const float* __restrict__ in,
                                                    u16* __restrict__ out, int n) {
    int i = (blockIdx.x * 256 + threadIdx.x) * 4;
    if (i >= n) return;
    float4 v = *reinterpret_cast<const float4*>(in + i);
    u16x4 o;
    o[0] = f2bf(v.x); o[1] = f2bf(v.y); o[2] = f2bf(v.z); o[3] = f2bf(v.w);
    *reinterpret_cast<u16x4*>(out + i) = o;
}

// ------------- transpose fp32[R][C] -> bf16[C][R] (LDS tile) -------------
__global__ __launch_bounds__(256) void transpose_cvt(const float* __restrict__ in,
                                                     u16* __restrict__ out, int R, int C) {
    __shared__ float tile[32][33];
    int c0 = blockIdx.x * 32, r0 = blockIdx.y * 32;
    int tx = threadIdx.x & 31, ty = threadIdx.x >> 5;   // 32 x 8
    #pragma unroll
    for (int i = ty; i < 32; i += 8)
        tile[i][tx] = in[(size_t)(r0 + i) * C + c0 + tx];
    __syncthreads();
    #pragma unroll
    for (int i = ty; i < 32; i += 8)
        out[(size_t)(c0 + i) * R + r0 + tx] = f2bf(tile[tx][i]);
}

// ------------- GEMM: C[M][N] = A[M][K] * Bt[N][K]^T + bias  (bf16 in, fp32 acc) -------------
// m97-style: 128x128 tile, 4 waves (2x2 of 64x64), BK=32, global_load_lds w=16.
template<int OUT_BF16>
__global__ __launch_bounds__(256) void gemm_bt(const u16* __restrict__ A,
                                               const u16* __restrict__ Bt,
                                               const float* __restrict__ bias,
                                               void* __restrict__ Cout,
                                               int Mtot, int Ntot, int K) {
    __shared__ __align__(16) u16 As[128 * 32];
    __shared__ __align__(16) u16 Bs[128 * 32];
    const int ntn = Ntot >> 7;
    const int tm = blockIdx.x / ntn, tn = blockIdx.x % ntn;
    const int m0 = tm << 7, n0 = tn << 7;
    const int tid = threadIdx.x, lane = tid & 63, w = tid >> 6;
    const int wm = (w >> 1) << 6, wn = (w & 1) << 6;
    // staging map: lane -> (row = lane>>2, col8 = (lane&3)*8); chunk = 16 rows (1024B)
    const int srow = lane >> 2, scol = (lane & 3) << 3;
    const int ch0 = w * 2;
    f32x4 acc[4][4] = {};
    const u16* gA = A + (size_t)(m0 + srow) * K + scol;
    const u16* gB = Bt + (size_t)(n0 + srow) * K + scol;

    for (int k0 = 0; k0 < K; k0 += 32) {
        #pragma unroll
        for (int c = 0; c < 2; ++c) {
            const int cc = ch0 + c;
            __builtin_amdgcn_global_load_lds((gptr_t)(gA + (size_t)(cc * 16) * K + k0),
                                             (lptr_t)(As + cc * 512), 16, 0, 0);
            __builtin_amdgcn_global_load_lds((gptr_t)(gB + (size_t)(cc * 16) * K + k0),
                                             (lptr_t)(Bs + cc * 512), 16, 0, 0);
        }
        __syncthreads();
        bf16x8 af[4], bfr[4];
        const int kofs = (lane >> 4) << 3;
        #pragma unroll
        for (int i = 0; i < 4; ++i) {
            af[i]  = *reinterpret_cast<const bf16x8*>(As + (wm + i * 16 + (lane & 15)) * 32 + kofs);
            bfr[i] = *reinterpret_cast<const bf16x8*>(Bs + (wn + i * 16 + (lane & 15)) * 32 + kofs);
        }
        #pragma unroll
        for (int mi = 0; mi < 4; ++mi)
            #pragma unroll
            for (int ni = 0; ni < 4; ++ni)
                acc[mi][ni] = __builtin_amdgcn_mfma_f32_16x16x32_bf16(af[mi], bfr[ni], acc[mi][ni], 0, 0, 0);
        __syncthreads();
    }

    // C/D layout (m89/m91 verified): col = lane&15, row = (lane>>4)*4 + r
    const int r0r = (lane >> 4) << 2, ccol = lane & 15;
    #pragma unroll
    for (int mi = 0; mi < 4; ++mi)
        #pragma unroll
        for (int ni = 0; ni < 4; ++ni) {
            const int col = n0 + wn + ni * 16 + ccol;
            const float bv = bias[col];
            #pragma unroll
            for (int r = 0; r < 4; ++r) {
                const int row = m0 + wm + mi * 16 + r0r + r;
                const float v = acc[mi][ni][r] + bv;
                if (OUT_BF16)
                    reinterpret_cast<u16*>(Cout)[(size_t)row * Ntot + col] = f2bf(v);
                else
                    reinterpret_cast<float*>(Cout)[(size_t)row * Ntot + col] = v;
            }
        }
}

// ------------- causal flash attention, vector fp32 (safe round-1) -------------
// grid (S/256, H, B), block 256. 1 q-row per thread; K/V tiles (64 x 64) staged to LDS fp32.
__global__ __launch_bounds__(256) void attn_fwd(const u16* __restrict__ qkv,
                                                u16* __restrict__ ctx) {
    __shared__ __align__(16) float Ks[64][64];
    __shared__ __align__(16) float Vs[64][64];
    const int b = blockIdx.z, h = blockIdx.y, q0 = blockIdx.x << 8;
    const int tid = threadIdx.x;
    const int q_idx = q0 + tid;

    // load q row into registers (fp32)
    float4 qv[16];
    {
        const u16* qrow = qkv + (size_t)(b * SS + q_idx) * NQKV + h * HDD;
        #pragma unroll
        for (int g = 0; g < 8; ++g) {
            u16x8 v = *reinterpret_cast<const u16x8*>(qrow + g * 8);
            float4 f0, f1;
            f0.x = bf2f(v[0]); f0.y = bf2f(v[1]); f0.z = bf2f(v[2]); f0.w = bf2f(v[3]);
            f1.x = bf2f(v[4]); f1.y = bf2f(v[5]); f1.z = bf2f(v[6]); f1.w = bf2f(v[7]);
            qv[g * 2] = f0; qv[g * 2 + 1] = f1;
        }
    }
    float4 ov[16];
    #pragma unroll
    for (int d = 0; d < 16; ++d) { ov[d].x = 0.f; ov[d].y = 0.f; ov[d].z = 0.f; ov[d].w = 0.f; }
    float mrun = -1e30f, lrun = 0.f;

    const int sj = tid >> 2, sd = (tid & 3) << 4;   // staging: row sj, 16 cols at sd

    for (int kc = 0; kc < q0 + 256; kc += 64) {
        __syncthreads();
        {
            const u16* kr = qkv + (size_t)(b * SS + kc + sj) * NQKV + DD + h * HDD + sd;
            const u16* vr = kr + DD;
            #pragma unroll
            for (int g = 0; g < 2; ++g) {
                u16x8 k8 = *reinterpret_cast<const u16x8*>(kr + g * 8);
                u16x8 v8 = *reinterpret_cast<const u16x8*>(vr + g * 8);
                #pragma unroll
                for (int t = 0; t < 8; ++t) {
                    Ks[sj][sd + g * 8 + t] = bf2f(k8[t]);
                    Vs[sj][sd + g * 8 + t] = bf2f(v8[t]);
                }
            }
        }
        __syncthreads();

        int jmax = q_idx - kc + 1;
        if (jmax > 64) jmax = 64;
        for (int j = 0; j < jmax; ++j) {
            const float4* krow4 = reinterpret_cast<const float4*>(&Ks[j][0]);
            float s0 = 0.f, s1 = 0.f, s2 = 0.f, s3 = 0.f;   // 4 parallel chains for ILP
            #pragma unroll
            for (int d = 0; d < 16; ++d) {
                float4 kk = krow4[d];
                s0 += qv[d].x * kk.x; s1 += qv[d].y * kk.y;
                s2 += qv[d].z * kk.z; s3 += qv[d].w * kk.w;
            }
            float s = (s0 + s1 + s2 + s3) * 0.125f;   // 1/sqrt(64)
            if (s > mrun) {                            // defer-max: rescale only on new max
                float corr = __expf(mrun - s);
                lrun *= corr;
                #pragma unroll
                for (int d = 0; d < 16; ++d) {
                    ov[d].x *= corr; ov[d].y *= corr; ov[d].z *= corr; ov[d].w *= corr;
                }
                mrun = s;
            }
            float p = __expf(s - mrun);
            lrun += p;
            const float4* vrow4 = reinterpret_cast<const float4*>(&Vs[j][0]);
            #pragma unroll
            for (int d = 0; d < 16; ++d) {
                float4 vv = vrow4[d];
                ov[d].x += p * vv.x; ov[d].y += p * vv.y;
                ov[d].z += p * vv.z; ov[d].w += p * vv.w;
            }
        }
    }

    const float inv = 1.0f / lrun;
    u16* orow = ctx + (size_t)(b * SS + q_idx) * DD + h * HDD;
    #pragma unroll
    for (int d = 0; d < 16; ++d) {
        u16x4 w4;
        w4[0] = f2bf(ov[d].x * inv); w4[1] = f2bf(ov[d].y * inv);
        w4[2] = f2bf(ov[d].z * inv); w4[3] = f2bf(ov[d].w * inv);
        *reinterpret_cast<u16x4*>(orow + d * 4) = w4;
    }
}

extern "C" void kernel_launch(void* const* d_in, const int* in_sizes, int n_in,
                              void* d_out, int out_size, void* d_ws, size_t ws_size,
                              hipStream_t stream) {
    const float* x     = (const float*)d_in[0];
    const float* W_qkv = (const float*)d_in[1];
    const float* b_qkv = (const float*)d_in[2];
    const float* W_out = (const float*)d_in[3];
    const float* b_out = (const float*)d_in[4];

    // workspace layout (bf16 u16 elements), total ~92.3 MB
    u16* xb    = (u16*)d_ws;                                  // [8192][1024]
    u16* Wqkvt = xb    + (size_t)MTOT * DD;                   // [3072][1024]
    u16* Wot   = Wqkvt + (size_t)NQKV * DD;                   // [1024][1024]
    u16* qkv   = Wot   + (size_t)DD * DD;                     // [8192][3072]
    u16* ctx   = qkv   + (size_t)MTOT * NQKV;                 // [8192][1024]

    // 1. convert x -> bf16
    cvt_f32_bf16<<<(MTOT * DD) / 1024, 256, 0, stream>>>(x, xb, MTOT * DD);
    // 2. transpose weights -> bf16 [N][K]
    transpose_cvt<<<dim3(NQKV / 32, DD / 32), 256, 0, stream>>>(W_qkv, Wqkvt, DD, NQKV);
    transpose_cvt<<<dim3(DD / 32, DD / 32), 256, 0, stream>>>(W_out, Wot, DD, DD);
    // 3. QKV projection: qkv = x @ W_qkv + b_qkv   (bf16 out)
    gemm_bt<1><<<(MTOT / 128) * (NQKV / 128), 256, 0, stream>>>(xb, Wqkvt, b_qkv, qkv, MTOT, NQKV, DD);
    // 4. causal flash attention -> ctx (bf16)
    attn_fwd<<<dim3(SS / 256, HH, BB), 256, 0, stream>>>(qkv, ctx);
    // 5. output projection: out = ctx @ W_out + b_out  (fp32 out)
    gemm_bt<0><<<(MTOT / 128) * (DD / 128), 256, 0, stream>>>(ctx, Wot, b_out, (float*)d_out, MTOT, DD, DD);
}

// Round 2
// 639.096 us; speedup vs baseline: 2.0882x; 2.0882x over previous
//
#include <hip/hip_runtime.h>
#include <stdint.h>

#define BB 4
#define SS 2048
#define DD 1024
#define HH 16
#define HDD 64
#define MTOT (BB*SS)      // 8192
#define NQKV (3*DD)       // 3072

typedef __bf16 bf16x8 __attribute__((ext_vector_type(8)));
typedef float  f32x4  __attribute__((ext_vector_type(4)));
typedef unsigned short u16;
typedef u16 u16x8 __attribute__((ext_vector_type(8)));
typedef u16 u16x4 __attribute__((ext_vector_type(4)));

typedef const __attribute__((address_space(1))) void* gptr_t;
typedef __attribute__((address_space(3))) void* lptr_t;

__device__ __forceinline__ u16 f2bf(float f) {
    uint32_t u = __builtin_bit_cast(uint32_t, f);
    u += 0x7FFFu + ((u >> 16) & 1u);   // RNE
    return (u16)(u >> 16);
}
__device__ __forceinline__ float bf2f(u16 v) {
    uint32_t u = ((uint32_t)v) << 16;
    return __builtin_bit_cast(float, u);
}

// ---------------- fp32 -> bf16 convert (vectorized) ----------------
__global__ __launch_bounds__(256) void cvt_f32_bf16(const float* __restrict__ in,
                                                    u16* __restrict__ out, int n) {
    int i = (blockIdx.x * 256 + threadIdx.x) * 4;
    if (i >= n) return;
    float4 v = *reinterpret_cast<const float4*>(in + i);
    u16x4 o;
    o[0] = f2bf(v.x); o[1] = f2bf(v.y); o[2] = f2bf(v.z); o[3] = f2bf(v.w);
    *reinterpret_cast<u16x4*>(out + i) = o;
}

// ------------- transpose fp32[R][C] -> bf16[C][R] (LDS tile) -------------
__global__ __launch_bounds__(256) void transpose_cvt(const float* __restrict__ in,
                                                     u16* __restrict__ out, int R, int C) {
    __shared__ float tile[32][33];
    int c0 = blockIdx.x * 32, r0 = blockIdx.y * 32;
    int tx = threadIdx.x & 31, ty = threadIdx.x >> 5;   // 32 x 8
    #pragma unroll
    for (int i = ty; i < 32; i += 8)
        tile[i][tx] = in[(size_t)(r0 + i) * C + c0 + tx];
    __syncthreads();
    #pragma unroll
    for (int i = ty; i < 32; i += 8)
        out[(size_t)(c0 + i) * R + r0 + tx] = f2bf(tile[tx][i]);
}

// ------------- GEMM: C[M][N] = A[M][K] * Bt[N][K]^T + bias  (bf16 in, fp32 acc) -------------
// m97-style: 128x128 tile, 4 waves (2x2 of 64x64), BK=32, global_load_lds w=16.
// SCALE_Q: multiply outputs in cols [0,1024) by 0.125 (folds attention 1/sqrt(64) into Q).
template<int OUT_BF16, int SCALE_Q>
__global__ __launch_bounds__(256) void gemm_bt(const u16* __restrict__ A,
                                               const u16* __restrict__ Bt,
                                               const float* __restrict__ bias,
                                               void* __restrict__ Cout,
                                               int Mtot, int Ntot, int K) {
    __shared__ __align__(16) u16 As[128 * 32];
    __shared__ __align__(16) u16 Bs[128 * 32];
    const int ntn = Ntot >> 7;
    const int tm = blockIdx.x / ntn, tn = blockIdx.x % ntn;
    const int m0 = tm << 7, n0 = tn << 7;
    const int tid = threadIdx.x, lane = tid & 63, w = tid >> 6;
    const int wm = (w >> 1) << 6, wn = (w & 1) << 6;
    const int srow = lane >> 2, scol = (lane & 3) << 3;
    const int ch0 = w * 2;
    f32x4 acc[4][4] = {};
    const u16* gA = A + (size_t)(m0 + srow) * K + scol;
    const u16* gB = Bt + (size_t)(n0 + srow) * K + scol;

    for (int k0 = 0; k0 < K; k0 += 32) {
        #pragma unroll
        for (int c = 0; c < 2; ++c) {
            const int cc = ch0 + c;
            __builtin_amdgcn_global_load_lds((gptr_t)(gA + (size_t)(cc * 16) * K + k0),
                                             (lptr_t)(As + cc * 512), 16, 0, 0);
            __builtin_amdgcn_global_load_lds((gptr_t)(gB + (size_t)(cc * 16) * K + k0),
                                             (lptr_t)(Bs + cc * 512), 16, 0, 0);
        }
        __syncthreads();
        bf16x8 af[4], bfr[4];
        const int kofs = (lane >> 4) << 3;
        #pragma unroll
        for (int i = 0; i < 4; ++i) {
            af[i]  = *reinterpret_cast<const bf16x8*>(As + (wm + i * 16 + (lane & 15)) * 32 + kofs);
            bfr[i] = *reinterpret_cast<const bf16x8*>(Bs + (wn + i * 16 + (lane & 15)) * 32 + kofs);
        }
        #pragma unroll
        for (int mi = 0; mi < 4; ++mi)
            #pragma unroll
            for (int ni = 0; ni < 4; ++ni)
                acc[mi][ni] = __builtin_amdgcn_mfma_f32_16x16x32_bf16(af[mi], bfr[ni], acc[mi][ni], 0, 0, 0);
        __syncthreads();
    }

    const int r0r = (lane >> 4) << 2, ccol = lane & 15;
    #pragma unroll
    for (int mi = 0; mi < 4; ++mi)
        #pragma unroll
        for (int ni = 0; ni < 4; ++ni) {
            const int col = n0 + wn + ni * 16 + ccol;
            const float bv = bias[col];
            #pragma unroll
            for (int r = 0; r < 4; ++r) {
                const int row = m0 + wm + mi * 16 + r0r + r;
                float v = acc[mi][ni][r] + bv;
                if (SCALE_Q && col < DD) v *= 0.125f;
                if (OUT_BF16)
                    reinterpret_cast<u16*>(Cout)[(size_t)row * Ntot + col] = f2bf(v);
                else
                    reinterpret_cast<float*>(Cout)[(size_t)row * Ntot + col] = v;
            }
        }
}

// ------------- MFMA causal flash attention -------------
// grid (S/128, H, B), block 256 = 4 waves. Each wave: 32 q-rows (2 x 16-row frag sets).
// KV tile = 64. K in LDS row-major [64][64] XOR-swizzled; V in LDS transposed [d][j]
// double-XOR-swizzled; P per-wave private LDS [16][64] XOR-swizzled.
__global__ __launch_bounds__(256) void attn_fwd2(const u16* __restrict__ qkv,
                                                 u16* __restrict__ ctx) {
    __shared__ __align__(16) char lds[24576];
    u16* Ks = (u16*)lds;              // 8 KB
    u16* Vt = (u16*)(lds + 8192);     // 8 KB
    u16* Pb = (u16*)(lds + 16384);    // 8 KB (2 KB per wave)

    const int b = blockIdx.z, h = blockIdx.y;
    const int q0 = blockIdx.x << 7;
    const int tid = threadIdx.x, lane = tid & 63, w = tid >> 6;
    const int g = lane >> 4, m = lane & 15;
    u16* Pw = Pb + w * 1024;
    const size_t bS = (size_t)b * SS;

    // Q fragments (Q pre-scaled by 0.125 in GEMM epilogue)
    bf16x8 qa[2][2];
    #pragma unroll
    for (int qs = 0; qs < 2; ++qs)
        #pragma unroll
        for (int ks = 0; ks < 2; ++ks) {
            const int row = q0 + 32 * w + 16 * qs + m;
            qa[qs][ks] = *reinterpret_cast<const bf16x8*>(
                qkv + (bS + row) * NQKV + h * HDD + ks * 32 + g * 8);
        }

    float mrow[2][4], lrow[2][4];
    f32x4 o[2][4] = {};
    #pragma unroll
    for (int qs = 0; qs < 2; ++qs)
        #pragma unroll
        for (int r = 0; r < 4; ++r) { mrow[qs][r] = -3e38f; lrow[qs][r] = 0.f; }

    // V staging map: pass p: j = 16w + 8p + (lane>>3), d0 = 8*(lane&7)
    const int vl3 = lane >> 3, vl7 = lane & 7;
    const int vd0 = vl7 << 3;

    const int ntiles = (q0 >> 6) + 2;
    for (int t = 0; t < ntiles; ++t) {
        const int kc = t << 6;
        __syncthreads();
        // ---- stage K via global_load_lds, source pre-swizzled (chunk ^= row&7) ----
        #pragma unroll
        for (int i = 0; i < 2; ++i) {
            const int C = w * 128 + i * 64 + lane;
            const int row = C >> 3, c = C & 7;
            const u16* src = qkv + (bS + kc + row) * NQKV + DD + h * HDD + ((c ^ (row & 7)) << 3);
            __builtin_amdgcn_global_load_lds((gptr_t)src, (lptr_t)(Ks + (size_t)(w * 128 + i * 64) * 8), 16, 0, 0);
        }
        // ---- stage V transposed: global u16x8 -> 8 x ds_write_b16, swizzle f(d)=e^(lane&7) ----
        #pragma unroll
        for (int p = 0; p < 2; ++p) {
            const int j = 16 * w + 8 * p + vl3;
            u16x8 vr = *reinterpret_cast<const u16x8*>(
                qkv + (bS + kc + j) * NQKV + 2 * DD + h * HDD + vd0);
            const int jc = j >> 3, jo = j & 7;
            #pragma unroll
            for (int e = 0; e < 8; ++e) {
                const int d = vd0 + e;
                const int cc = (jc ^ e ^ vl7) & 7;
                Vt[d * 64 + cc * 8 + jo] = vr[e];
            }
        }
        __syncthreads();

        // per-qs status
        int base0 = q0 + 32 * w - kc;
        int base[2] = { base0, base0 + 16 };
        bool skip[2], full[2];
        #pragma unroll
        for (int qs = 0; qs < 2; ++qs) { skip[qs] = (base[qs] + 15 < 0); full[qs] = (base[qs] >= 63); }

        // ---- QK^T ----
        f32x4 acc[2][4] = {};
        #pragma unroll
        for (int nj = 0; nj < 4; ++nj) {
            const int row = nj * 16 + m;
            #pragma unroll
            for (int ks = 0; ks < 2; ++ks) {
                const int c = (g + 4 * ks) ^ (row & 7);
                bf16x8 kb = *reinterpret_cast<const bf16x8*>(Ks + row * 64 + c * 8);
                if (!skip[0]) acc[0][nj] = __builtin_amdgcn_mfma_f32_16x16x32_bf16(qa[0][ks], kb, acc[0][nj], 0, 0, 0);
                if (!skip[1]) acc[1][nj] = __builtin_amdgcn_mfma_f32_16x16x32_bf16(qa[1][ks], kb, acc[1][nj], 0, 0, 0);
            }
        }

        // ---- softmax + P store + P-frag read, per qs ----
        bf16x8 pa[2][2];
        #pragma unroll
        for (int qs = 0; qs < 2; ++qs) {
            if (skip[qs]) continue;
            if (!full[qs]) {
                #pragma unroll
                for (int nj = 0; nj < 4; ++nj)
                    #pragma unroll
                    for (int r = 0; r < 4; ++r) {
                        const bool keep = (16 * nj + m - 4 * g - r) <= base[qs];
                        acc[qs][nj][r] = keep ? acc[qs][nj][r] : -3e38f;
                    }
            }
            float tmax[4];
            #pragma unroll
            for (int r = 0; r < 4; ++r)
                tmax[r] = fmaxf(fmaxf(acc[qs][0][r], acc[qs][1][r]), fmaxf(acc[qs][2][r], acc[qs][3][r]));
            #pragma unroll
            for (int msk = 1; msk <= 8; msk <<= 1)
                #pragma unroll
                for (int r = 0; r < 4; ++r)
                    tmax[r] = fmaxf(tmax[r], __shfl_xor(tmax[r], msk));
            float corr[4];
            #pragma unroll
            for (int r = 0; r < 4; ++r) {
                const float mn = fmaxf(mrow[qs][r], tmax[r]);
                corr[r] = __expf(mrow[qs][r] - mn);
                mrow[qs][r] = mn;
            }
            float ps[4] = {0.f, 0.f, 0.f, 0.f};
            #pragma unroll
            for (int nj = 0; nj < 4; ++nj)
                #pragma unroll
                for (int r = 0; r < 4; ++r) {
                    const float p = __expf(acc[qs][nj][r] - mrow[qs][r]);
                    acc[qs][nj][r] = p;
                    ps[r] += p;
                }
            #pragma unroll
            for (int msk = 1; msk <= 8; msk <<= 1)
                #pragma unroll
                for (int r = 0; r < 4; ++r)
                    ps[r] += __shfl_xor(ps[r], msk);
            #pragma unroll
            for (int r = 0; r < 4; ++r)
                lrow[qs][r] = lrow[qs][r] * corr[r] + ps[r];
            #pragma unroll
            for (int dg = 0; dg < 4; ++dg)
                #pragma unroll
                for (int r = 0; r < 4; ++r)
                    o[qs][dg][r] *= corr[r];
            // store P (swizzled), read back as A-frags
            #pragma unroll
            for (int nj = 0; nj < 4; ++nj)
                #pragma unroll
                for (int r = 0; r < 4; ++r) {
                    const int row = 4 * g + r, col = 16 * nj + m;
                    const int c = (col >> 3) ^ (row & 7);
                    Pw[row * 64 + c * 8 + (col & 7)] = f2bf(acc[qs][nj][r]);
                }
            #pragma unroll
            for (int ks = 0; ks < 2; ++ks) {
                const int c = (g + 4 * ks) ^ (m & 7);
                pa[qs][ks] = *reinterpret_cast<const bf16x8*>(Pw + m * 64 + c * 8);
            }
        }

        // ---- PV ----
        #pragma unroll
        for (int dg = 0; dg < 4; ++dg) {
            const int row = 16 * dg + m;
            const int f = (m & 7) ^ ((2 * dg + (m >> 3)) & 7);
            #pragma unroll
            for (int ks = 0; ks < 2; ++ks) {
                const int c = (g + 4 * ks) ^ f;
                bf16x8 vb = *reinterpret_cast<const bf16x8*>(Vt + row * 64 + c * 8);
                if (!skip[0]) o[0][dg] = __builtin_amdgcn_mfma_f32_16x16x32_bf16(pa[0][ks], vb, o[0][dg], 0, 0, 0);
                if (!skip[1]) o[1][dg] = __builtin_amdgcn_mfma_f32_16x16x32_bf16(pa[1][ks], vb, o[1][dg], 0, 0, 0);
            }
        }
    }

    // ---- epilogue ----
    #pragma unroll
    for (int qs = 0; qs < 2; ++qs) {
        float inv[4];
        #pragma unroll
        for (int r = 0; r < 4; ++r) inv[r] = 1.0f / lrow[qs][r];
        #pragma unroll
        for (int dg = 0; dg < 4; ++dg)
            #pragma unroll
            for (int r = 0; r < 4; ++r) {
                const int row = q0 + 32 * w + 16 * qs + 4 * g + r;
                ctx[(bS + row) * DD + h * HDD + 16 * dg + m] = f2bf(o[qs][dg][r] * inv[r]);
            }
    }
}

extern "C" void kernel_launch(void* const* d_in, const int* in_sizes, int n_in,
                              void* d_out, int out_size, void* d_ws, size_t ws_size,
                              hipStream_t stream) {
    const float* x     = (const float*)d_in[0];
    const float* W_qkv = (const float*)d_in[1];
    const float* b_qkv = (const float*)d_in[2];
    const float* W_out = (const float*)d_in[3];
    const float* b_out = (const float*)d_in[4];

    u16* xb    = (u16*)d_ws;                                  // [8192][1024]
    u16* Wqkvt = xb    + (size_t)MTOT * DD;                   // [3072][1024]
    u16* Wot   = Wqkvt + (size_t)NQKV * DD;                   // [1024][1024]
    u16* qkv   = Wot   + (size_t)DD * DD;                     // [8192][3072]
    u16* ctx   = qkv   + (size_t)MTOT * NQKV;                 // [8192][1024]

    cvt_f32_bf16<<<(MTOT * DD) / 1024, 256, 0, stream>>>(x, xb, MTOT * DD);
    transpose_cvt<<<dim3(NQKV / 32, DD / 32), 256, 0, stream>>>(W_qkv, Wqkvt, DD, NQKV);
    transpose_cvt<<<dim3(DD / 32, DD / 32), 256, 0, stream>>>(W_out, Wot, DD, DD);
    gemm_bt<1, 1><<<(MTOT / 128) * (NQKV / 128), 256, 0, stream>>>(xb, Wqkvt, b_qkv, qkv, MTOT, NQKV, DD);
    attn_fwd2<<<dim3(SS / 128, HH, BB), 256, 0, stream>>>(qkv, ctx);
    gemm_bt<0, 0><<<(MTOT / 128) * (DD / 128), 256, 0, stream>>>(ctx, Wot, b_out, (float*)d_out, MTOT, DD, DD);
}

// Round 6
// 354.301 us; speedup vs baseline: 3.7667x; 1.8038x over previous
//
#include <hip/hip_runtime.h>
#include <stdint.h>

#define BB 4
#define SS 2048
#define DD 1024
#define HH 16
#define HDD 64
#define MTOT (BB*SS)      // 8192
#define NQKV (3*DD)       // 3072

typedef __bf16 bf16x8 __attribute__((ext_vector_type(8)));
typedef float  f32x4  __attribute__((ext_vector_type(4)));
typedef unsigned short u16;
typedef u16 u16x8 __attribute__((ext_vector_type(8)));
typedef u16 u16x4 __attribute__((ext_vector_type(4)));

typedef const __attribute__((address_space(1))) void* gptr_t;
typedef __attribute__((address_space(3))) void* lptr_t;

__device__ __forceinline__ u16 f2bf(float f) {
    uint32_t u = __builtin_bit_cast(uint32_t, f);
    u += 0x7FFFu + ((u >> 16) & 1u);   // RNE
    return (u16)(u >> 16);
}
__device__ __forceinline__ float bf2f(u16 v) {
    uint32_t u = ((uint32_t)v) << 16;
    return __builtin_bit_cast(float, u);
}

// ---------------- fp32 -> bf16 convert (vectorized) ----------------
__global__ __launch_bounds__(256) void cvt_f32_bf16(const float* __restrict__ in,
                                                    u16* __restrict__ out, int n) {
    int i = (blockIdx.x * 256 + threadIdx.x) * 4;
    if (i >= n) return;
    float4 v = *reinterpret_cast<const float4*>(in + i);
    u16x4 o;
    o[0] = f2bf(v.x); o[1] = f2bf(v.y); o[2] = f2bf(v.z); o[3] = f2bf(v.w);
    *reinterpret_cast<u16x4*>(out + i) = o;
}

// ------------- transpose fp32[R][C] -> bf16[C][R] (LDS tile) -------------
__global__ __launch_bounds__(256) void transpose_cvt(const float* __restrict__ in,
                                                     u16* __restrict__ out, int R, int C) {
    __shared__ float tile[32][33];
    int c0 = blockIdx.x * 32, r0 = blockIdx.y * 32;
    int tx = threadIdx.x & 31, ty = threadIdx.x >> 5;   // 32 x 8
    #pragma unroll
    for (int i = ty; i < 32; i += 8)
        tile[i][tx] = in[(size_t)(r0 + i) * C + c0 + tx];
    __syncthreads();
    #pragma unroll
    for (int i = ty; i < 32; i += 8)
        out[(size_t)(c0 + i) * R + r0 + tx] = f2bf(tile[tx][i]);
}

// ------------- GEMM: C[M][N] = A[M][K] * Bt[N][K]^T + bias  (bf16 in, fp32 acc) -------------
template<int OUT_BF16, int SCALE_Q>
__global__ __launch_bounds__(256) void gemm_bt(const u16* __restrict__ A,
                                               const u16* __restrict__ Bt,
                                               const float* __restrict__ bias,
                                               void* __restrict__ Cout,
                                               int Mtot, int Ntot, int K) {
    __shared__ __align__(16) u16 As[128 * 32];
    __shared__ __align__(16) u16 Bs[128 * 32];
    const int ntn = Ntot >> 7;
    const int tm = blockIdx.x / ntn, tn = blockIdx.x % ntn;
    const int m0 = tm << 7, n0 = tn << 7;
    const int tid = threadIdx.x, lane = tid & 63, w = tid >> 6;
    const int wm = (w >> 1) << 6, wn = (w & 1) << 6;
    const int srow = lane >> 2, scol = (lane & 3) << 3;
    const int ch0 = w * 2;
    f32x4 acc[4][4] = {};
    const u16* gA = A + (size_t)(m0 + srow) * K + scol;
    const u16* gB = Bt + (size_t)(n0 + srow) * K + scol;

    for (int k0 = 0; k0 < K; k0 += 32) {
        #pragma unroll
        for (int c = 0; c < 2; ++c) {
            const int cc = ch0 + c;
            __builtin_amdgcn_global_load_lds((gptr_t)(gA + (size_t)(cc * 16) * K + k0),
                                             (lptr_t)(As + cc * 512), 16, 0, 0);
            __builtin_amdgcn_global_load_lds((gptr_t)(gB + (size_t)(cc * 16) * K + k0),
                                             (lptr_t)(Bs + cc * 512), 16, 0, 0);
        }
        __syncthreads();
        bf16x8 af[4], bfr[4];
        const int kofs = (lane >> 4) << 3;
        #pragma unroll
        for (int i = 0; i < 4; ++i) {
            af[i]  = *reinterpret_cast<const bf16x8*>(As + (wm + i * 16 + (lane & 15)) * 32 + kofs);
            bfr[i] = *reinterpret_cast<const bf16x8*>(Bs + (wn + i * 16 + (lane & 15)) * 32 + kofs);
        }
        #pragma unroll
        for (int mi = 0; mi < 4; ++mi)
            #pragma unroll
            for (int ni = 0; ni < 4; ++ni)
                acc[mi][ni] = __builtin_amdgcn_mfma_f32_16x16x32_bf16(af[mi], bfr[ni], acc[mi][ni], 0, 0, 0);
        __syncthreads();
    }

    const int r0r = (lane >> 4) << 2, ccol = lane & 15;
    #pragma unroll
    for (int mi = 0; mi < 4; ++mi)
        #pragma unroll
        for (int ni = 0; ni < 4; ++ni) {
            const int col = n0 + wn + ni * 16 + ccol;
            const float bv = bias[col];
            #pragma unroll
            for (int r = 0; r < 4; ++r) {
                const int row = m0 + wm + mi * 16 + r0r + r;
                float v = acc[mi][ni][r] + bv;
                if (SCALE_Q && col < DD) v *= 0.125f;
                if (OUT_BF16)
                    reinterpret_cast<u16*>(Cout)[(size_t)row * Ntot + col] = f2bf(v);
                else
                    reinterpret_cast<float*>(Cout)[(size_t)row * Ntot + col] = v;
            }
        }
}

// ------------- MFMA causal flash attention, swapped-QK^T, in-register softmax -------------
// grid (S/128, H, B), block 256 = 4 waves; heavy-first bx remap.
// Conservative fwd2-proven sync shape: per tile {barrier; stage K(DMA)+V(reg->LDS); barrier; compute}.
// S^T = mfma(K, Q): lane holds S[k(4g+r per nj)][q=m]. P stays in registers; V's LDS layout
// absorbs the P k-slot permutation so PV needs zero shuffles.
__global__ __launch_bounds__(256) void attn_fwd4(const u16* __restrict__ qkv,
                                                 u16* __restrict__ ctx) {
    __shared__ __align__(16) u16 Ks[64 * 64];   // 8 KB, chunk-swizzled
    __shared__ __align__(16) u16 Vt[64 * 64];   // 8 KB, slot-permuted + XOR-swizzled

    const int b = blockIdx.z, h = blockIdx.y;
    const int bx = (int)gridDim.x - 1 - (int)blockIdx.x;   // heavy blocks first
    const int q0 = bx << 7;
    const int tid = threadIdx.x, lane = tid & 63, w = tid >> 6;
    const int g = lane >> 4, m = lane & 15;
    const size_t bS = (size_t)b * SS;

    // Q fragments (B-operand): lane holds Q[q0+32w+16qs+m][32ks+8g .. +7]; pre-scaled by 0.125
    bf16x8 qa[2][2];
    #pragma unroll
    for (int qs = 0; qs < 2; ++qs)
        #pragma unroll
        for (int ks = 0; ks < 2; ++ks)
            qa[qs][ks] = *reinterpret_cast<const bf16x8*>(
                qkv + (bS + q0 + 32 * w + 16 * qs + m) * NQKV + h * HDD + ks * 32 + g * 8);

    float mrow[2] = {-3e38f, -3e38f}, lrow[2] = {0.f, 0.f};
    f32x4 o[2][4] = {};

    const int vl3 = lane >> 3, vl7 = lane & 7;
    const int vd0 = vl7 << 3;

    const int ntiles = (q0 >> 6) + 2;

    for (int t = 0; t < ntiles; ++t) {
        const int kc = t << 6;

        __syncthreads();    // prior tile's Ks/Vt reads complete

        // ---- stage K via global_load_lds, source pre-swizzled (chunk ^= row&7) ----
        #pragma unroll
        for (int i = 0; i < 2; ++i) {
            const int C = w * 128 + i * 64 + lane;
            const int row = C >> 3, c = C & 7;
            const u16* src = qkv + (bS + kc + row) * NQKV + DD + h * HDD + ((c ^ (row & 7)) << 3);
            __builtin_amdgcn_global_load_lds((gptr_t)src,
                                             (lptr_t)(Ks + (size_t)(w * 128 + i * 64) * 8), 16, 0, 0);
        }
        // ---- stage V transposed + slot-permuted: global u16x8 -> 8 x ds_write_b16 ----
        #pragma unroll
        for (int p = 0; p < 2; ++p) {
            const int j = 16 * w + 8 * p + vl3;
            u16x8 vr = *reinterpret_cast<const u16x8*>(
                qkv + (bS + kc + j) * NQKV + 2 * DD + h * HDD + vd0);
            const int sj = 32 * (j >> 5) + 8 * ((j >> 2) & 3) + 4 * ((j >> 4) & 1) + (j & 3);
            #pragma unroll
            for (int e = 0; e < 8; ++e) {
                const int sw = (e ^ vl7) & 7;          // (d&7)=e, d>>3=vl7
                Vt[(vd0 + e) * 64 + (sj ^ (sw << 3))] = vr[e];
            }
        }

        __syncthreads();    // K DMA drained + V ds_writes visible

        const int base_[2] = {q0 + 32 * w - kc, q0 + 32 * w - kc + 16};
        const bool skip0 = (base_[0] + 15) < 0, skip1 = (base_[1] + 15) < 0;
        if (skip0 && skip1) continue;   // wave-uniform; barriers are at loop top

        // ---- K A-frags from LDS (chunk-swizzled rows) ----
        bf16x8 kb[4][2];
        #pragma unroll
        for (int nj = 0; nj < 4; ++nj) {
            const int row = nj * 16 + m;
            #pragma unroll
            for (int ks = 0; ks < 2; ++ks) {
                const int c = (g + 4 * ks) ^ (row & 7);
                kb[nj][ks] = *reinterpret_cast<const bf16x8*>(Ks + row * 64 + c * 8);
            }
        }
        // ---- S^T = K·Q^T : row(4g+r)=k, col(m)=q ----
        f32x4 acc[2][4] = {};
        #pragma unroll
        for (int nj = 0; nj < 4; ++nj)
            #pragma unroll
            for (int ks = 0; ks < 2; ++ks) {
                if (!skip0) acc[0][nj] = __builtin_amdgcn_mfma_f32_16x16x32_bf16(kb[nj][ks], qa[0][ks], acc[0][nj], 0, 0, 0);
                if (!skip1) acc[1][nj] = __builtin_amdgcn_mfma_f32_16x16x32_bf16(kb[nj][ks], qa[1][ks], acc[1][nj], 0, 0, 0);
            }

        // ---- in-register softmax (q = m per lane), defer-max ----
        bf16x8 pa[2][2];
        #pragma unroll
        for (int qs = 0; qs < 2; ++qs) {
            const bool skq = qs ? skip1 : skip0;
            if (skq) continue;                       // wave-uniform
            if (base_[qs] < 63) {                    // diagonal tile: causal mask
                #pragma unroll
                for (int nj = 0; nj < 4; ++nj)
                    #pragma unroll
                    for (int r = 0; r < 4; ++r)
                        if (16 * nj + 4 * g + r - m > base_[qs]) acc[qs][nj][r] = -3e38f;
            }
            float tmax = -3e38f;
            #pragma unroll
            for (int nj = 0; nj < 4; ++nj)
                #pragma unroll
                for (int r = 0; r < 4; ++r) tmax = fmaxf(tmax, acc[qs][nj][r]);
            tmax = fmaxf(tmax, __shfl_xor(tmax, 16));
            tmax = fmaxf(tmax, __shfl_xor(tmax, 32));
            if (!__all(tmax <= mrow[qs] + 8.f)) {    // T13 defer-max
                const float mn = fmaxf(mrow[qs], tmax);
                const float corr = __expf(mrow[qs] - mn);
                mrow[qs] = mn;
                lrow[qs] *= corr;
                float c4[4];
                #pragma unroll
                for (int r = 0; r < 4; ++r) c4[r] = __shfl(corr, 4 * g + r);
                #pragma unroll
                for (int dg = 0; dg < 4; ++dg)
                    #pragma unroll
                    for (int r = 0; r < 4; ++r) o[qs][dg][r] *= c4[r];
            }
            float ssum = 0.f;
            #pragma unroll
            for (int nj = 0; nj < 4; ++nj)
                #pragma unroll
                for (int r = 0; r < 4; ++r) {
                    const float p = __expf(acc[qs][nj][r] - mrow[qs]);
                    acc[qs][nj][r] = p;
                    ssum += p;
                }
            ssum += __shfl_xor(ssum, 16);
            ssum += __shfl_xor(ssum, 32);
            lrow[qs] += ssum;
            // pack P A-frags: slot (g,e): e<4 -> acc[2ks][e] (k=32ks+4g+e), e>=4 -> acc[2ks+1][e-4]
            #pragma unroll
            for (int ks = 0; ks < 2; ++ks) {
                u16x8 pk;
                #pragma unroll
                for (int r = 0; r < 4; ++r) {
                    pk[r]     = f2bf(acc[qs][2 * ks][r]);
                    pk[r + 4] = f2bf(acc[qs][2 * ks + 1][r]);
                }
                pa[qs][ks] = __builtin_bit_cast(bf16x8, pk);
            }
        }

        // ---- PV: O[q(4g+r)][d(m)] += P·V, V slots match pa's k-permutation ----
        #pragma unroll
        for (int dg = 0; dg < 4; ++dg) {
            const int d = 16 * dg + m;
            const int sw = ((d & 7) ^ (d >> 3)) & 7;
            #pragma unroll
            for (int ks = 0; ks < 2; ++ks) {
                const int sb = (32 * ks + 8 * g) ^ (sw << 3);
                bf16x8 vb = *reinterpret_cast<const bf16x8*>(Vt + d * 64 + sb);
                if (!skip0) o[0][dg] = __builtin_amdgcn_mfma_f32_16x16x32_bf16(pa[0][ks], vb, o[0][dg], 0, 0, 0);
                if (!skip1) o[1][dg] = __builtin_amdgcn_mfma_f32_16x16x32_bf16(pa[1][ks], vb, o[1][dg], 0, 0, 0);
            }
        }
    }

    // ---- epilogue: redistribute l (q=m lanes -> q=4g+r lanes), normalize, store ----
    #pragma unroll
    for (int qs = 0; qs < 2; ++qs) {
        float linv[4];
        #pragma unroll
        for (int r = 0; r < 4; ++r) linv[r] = 1.0f / __shfl(lrow[qs], 4 * g + r);
        #pragma unroll
        for (int dg = 0; dg < 4; ++dg)
            #pragma unroll
            for (int r = 0; r < 4; ++r) {
                const int row = q0 + 32 * w + 16 * qs + 4 * g + r;
                ctx[(bS + row) * DD + h * HDD + 16 * dg + m] = f2bf(o[qs][dg][r] * linv[r]);
            }
    }
}

extern "C" void kernel_launch(void* const* d_in, const int* in_sizes, int n_in,
                              void* d_out, int out_size, void* d_ws, size_t ws_size,
                              hipStream_t stream) {
    const float* x     = (const float*)d_in[0];
    const float* W_qkv = (const float*)d_in[1];
    const float* b_qkv = (const float*)d_in[2];
    const float* W_out = (const float*)d_in[3];
    const float* b_out = (const float*)d_in[4];

    u16* xb    = (u16*)d_ws;                                  // [8192][1024]
    u16* Wqkvt = xb    + (size_t)MTOT * DD;                   // [3072][1024]
    u16* Wot   = Wqkvt + (size_t)NQKV * DD;                   // [1024][1024]
    u16* qkv   = Wot   + (size_t)DD * DD;                     // [8192][3072]
    u16* ctx   = qkv   + (size_t)MTOT * NQKV;                 // [8192][1024]

    cvt_f32_bf16<<<(MTOT * DD) / 1024, 256, 0, stream>>>(x, xb, MTOT * DD);
    transpose_cvt<<<dim3(NQKV / 32, DD / 32), 256, 0, stream>>>(W_qkv, Wqkvt, DD, NQKV);
    transpose_cvt<<<dim3(DD / 32, DD / 32), 256, 0, stream>>>(W_out, Wot, DD, DD);
    gemm_bt<1, 1><<<(MTOT / 128) * (NQKV / 128), 256, 0, stream>>>(xb, Wqkvt, b_qkv, qkv, MTOT, NQKV, DD);
    attn_fwd4<<<dim3(SS / 128, HH, BB), 256, 0, stream>>>(qkv, ctx);
    gemm_bt<0, 0><<<(MTOT / 128) * (DD / 128), 256, 0, stream>>>(ctx, Wot, b_out, (float*)d_out, MTOT, DD, DD);
}

// Round 10
// 348.141 us; speedup vs baseline: 3.8333x; 1.0177x over previous
//
#include <hip/hip_runtime.h>
#include <stdint.h>

#define BB 4
#define SS 2048
#define DD 1024
#define HH 16
#define HDD 64
#define MTOT (BB*SS)      // 8192
#define NQKV (3*DD)       // 3072

typedef __bf16 bf16x8 __attribute__((ext_vector_type(8)));
typedef float  f32x4  __attribute__((ext_vector_type(4)));
typedef unsigned short u16;
typedef u16 u16x8 __attribute__((ext_vector_type(8)));
typedef u16 u16x4 __attribute__((ext_vector_type(4)));

typedef const __attribute__((address_space(1))) void* gptr_t;
typedef __attribute__((address_space(3))) void* lptr_t;

__device__ __forceinline__ u16 f2bf(float f) {
    uint32_t u = __builtin_bit_cast(uint32_t, f);
    u += 0x7FFFu + ((u >> 16) & 1u);   // RNE
    return (u16)(u >> 16);
}
__device__ __forceinline__ float bf2f(u16 v) {
    uint32_t u = ((uint32_t)v) << 16;
    return __builtin_bit_cast(float, u);
}

// ---------------- fp32 -> bf16 convert (vectorized) ----------------
__global__ __launch_bounds__(256) void cvt_f32_bf16(const float* __restrict__ in,
                                                    u16* __restrict__ out, int n) {
    int i = (blockIdx.x * 256 + threadIdx.x) * 4;
    if (i >= n) return;
    float4 v = *reinterpret_cast<const float4*>(in + i);
    u16x4 o;
    o[0] = f2bf(v.x); o[1] = f2bf(v.y); o[2] = f2bf(v.z); o[3] = f2bf(v.w);
    *reinterpret_cast<u16x4*>(out + i) = o;
}

// ------------- transpose fp32[R][C] -> bf16[C][R] (LDS tile) -------------
__global__ __launch_bounds__(256) void transpose_cvt(const float* __restrict__ in,
                                                     u16* __restrict__ out, int R, int C) {
    __shared__ float tile[32][33];
    int c0 = blockIdx.x * 32, r0 = blockIdx.y * 32;
    int tx = threadIdx.x & 31, ty = threadIdx.x >> 5;   // 32 x 8
    #pragma unroll
    for (int i = ty; i < 32; i += 8)
        tile[i][tx] = in[(size_t)(r0 + i) * C + c0 + tx];
    __syncthreads();
    #pragma unroll
    for (int i = ty; i < 32; i += 8)
        out[(size_t)(c0 + i) * R + r0 + tx] = f2bf(tile[tx][i]);
}

// ------------- GEMM: C[M][N] = A[M][K] * Bt[N][K]^T + bias  (bf16 in, fp32 acc) -------------
template<int OUT_BF16, int SCALE_Q>
__global__ __launch_bounds__(256) void gemm_bt(const u16* __restrict__ A,
                                               const u16* __restrict__ Bt,
                                               const float* __restrict__ bias,
                                               void* __restrict__ Cout,
                                               int Mtot, int Ntot, int K) {
    __shared__ __align__(16) u16 As[128 * 32];
    __shared__ __align__(16) u16 Bs[128 * 32];
    const int ntn = Ntot >> 7;
    const int tm = blockIdx.x / ntn, tn = blockIdx.x % ntn;
    const int m0 = tm << 7, n0 = tn << 7;
    const int tid = threadIdx.x, lane = tid & 63, w = tid >> 6;
    const int wm = (w >> 1) << 6, wn = (w & 1) << 6;
    const int srow = lane >> 2, scol = (lane & 3) << 3;
    const int ch0 = w * 2;
    f32x4 acc[4][4] = {};
    const u16* gA = A + (size_t)(m0 + srow) * K + scol;
    const u16* gB = Bt + (size_t)(n0 + srow) * K + scol;

    for (int k0 = 0; k0 < K; k0 += 32) {
        #pragma unroll
        for (int c = 0; c < 2; ++c) {
            const int cc = ch0 + c;
            __builtin_amdgcn_global_load_lds((gptr_t)(gA + (size_t)(cc * 16) * K + k0),
                                             (lptr_t)(As + cc * 512), 16, 0, 0);
            __builtin_amdgcn_global_load_lds((gptr_t)(gB + (size_t)(cc * 16) * K + k0),
                                             (lptr_t)(Bs + cc * 512), 16, 0, 0);
        }
        __syncthreads();
        bf16x8 af[4], bfr[4];
        const int kofs = (lane >> 4) << 3;
        #pragma unroll
        for (int i = 0; i < 4; ++i) {
            af[i]  = *reinterpret_cast<const bf16x8*>(As + (wm + i * 16 + (lane & 15)) * 32 + kofs);
            bfr[i] = *reinterpret_cast<const bf16x8*>(Bs + (wn + i * 16 + (lane & 15)) * 32 + kofs);
        }
        #pragma unroll
        for (int mi = 0; mi < 4; ++mi)
            #pragma unroll
            for (int ni = 0; ni < 4; ++ni)
                acc[mi][ni] = __builtin_amdgcn_mfma_f32_16x16x32_bf16(af[mi], bfr[ni], acc[mi][ni], 0, 0, 0);
        __syncthreads();
    }

    const int r0r = (lane >> 4) << 2, ccol = lane & 15;
    #pragma unroll
    for (int mi = 0; mi < 4; ++mi)
        #pragma unroll
        for (int ni = 0; ni < 4; ++ni) {
            const int col = n0 + wn + ni * 16 + ccol;
            const float bv = bias[col];
            #pragma unroll
            for (int r = 0; r < 4; ++r) {
                const int row = m0 + wm + mi * 16 + r0r + r;
                float v = acc[mi][ni][r] + bv;
                if (SCALE_Q && col < DD) v *= 0.125f;
                if (OUT_BF16)
                    reinterpret_cast<u16*>(Cout)[(size_t)row * Ntot + col] = f2bf(v);
                else
                    reinterpret_cast<float*>(Cout)[(size_t)row * Ntot + col] = v;
            }
        }
}

// ------------- MFMA causal flash attention, KVBLK=128, swapped-QK^T, in-reg softmax -------------
// grid (S/128, H, B), block 256 = 4 waves; heavy-first bx remap.
// Race-free sync shape per 128 KV rows: {barrier; stage K(4 DMA)+V(4 loads + 32 LDS writes);
// barrier; compute sub-tile 0; compute sub-tile 1}. S^T = mfma(K,Q): lane holds S[k][q=m].
// P stays in registers; V's LDS layout absorbs the P k-slot permutation (zero shuffles).
__global__ __launch_bounds__(256) void attn_fwd5(const u16* __restrict__ qkv,
                                                 u16* __restrict__ ctx) {
    __shared__ __align__(16) u16 Ks[128 * 64];   // 16 KB, row-chunk-swizzled
    __shared__ __align__(16) u16 Vt[64 * 128];   // 16 KB, [d][2 x 64-slot blocks], permuted+swizzled

    const int b = blockIdx.z, h = blockIdx.y;
    const int bx = (int)gridDim.x - 1 - (int)blockIdx.x;   // heavy blocks first
    const int q0 = bx << 7;
    const int tid = threadIdx.x, lane = tid & 63, w = tid >> 6;
    const int g = lane >> 4, m = lane & 15;
    const size_t bS = (size_t)b * SS;

    // Q fragments (B-operand): lane holds Q[q0+32w+16qs+m][32ks+8g .. +7]; pre-scaled by 0.125
    bf16x8 qa[2][2];
    #pragma unroll
    for (int qs = 0; qs < 2; ++qs)
        #pragma unroll
        for (int ks = 0; ks < 2; ++ks)
            qa[qs][ks] = *reinterpret_cast<const bf16x8*>(
                qkv + (bS + q0 + 32 * w + 16 * qs + m) * NQKV + h * HDD + ks * 32 + g * 8);

    float mrow[2] = {-3e38f, -3e38f}, lrow[2] = {0.f, 0.f};
    f32x4 o[2][4] = {};

    const int vl3 = lane >> 3, vl7 = lane & 7;
    const int vd0 = vl7 << 3;

    const int ntiles = bx + 1;    // KV limit = q0 + 128 = 128 * (bx+1)

    for (int t = 0; t < ntiles; ++t) {
        const int kc = t << 7;

        __syncthreads();    // prior tile's Ks/Vt reads complete

        // ---- stage K (128 rows) via global_load_lds, source pre-swizzled (chunk ^= row&7) ----
        #pragma unroll
        for (int i = 0; i < 4; ++i) {
            const int C = w * 256 + i * 64 + lane;        // chunk id, 8 chunks/row
            const int row = C >> 3, c = C & 7;
            const u16* src = qkv + (bS + kc + row) * NQKV + DD + h * HDD + ((c ^ (row & 7)) << 3);
            __builtin_amdgcn_global_load_lds((gptr_t)src,
                                             (lptr_t)(Ks + (size_t)(w * 256 + i * 64) * 8), 16, 0, 0);
        }
        // ---- stage V (128 rows) transposed + slot-permuted ----
        u16x8 vr[4];
        #pragma unroll
        for (int p = 0; p < 4; ++p)
            vr[p] = *reinterpret_cast<const u16x8*>(
                qkv + (bS + kc + 32 * w + 8 * p + vl3) * NQKV + 2 * DD + h * HDD + vd0);
        #pragma unroll
        for (int p = 0; p < 4; ++p) {
            const int j = 32 * w + 8 * p + vl3;
            const int sub = j >> 6, j64 = j & 63;
            const int sj = 32 * (j64 >> 5) + 8 * ((j64 >> 2) & 3) + 4 * ((j64 >> 4) & 1) + (j64 & 3);
            #pragma unroll
            for (int e = 0; e < 8; ++e) {
                const int sw = (e ^ vl7) & 7;          // (d&7)=e, d>>3=vl7
                Vt[(vd0 + e) * 128 + sub * 64 + (sj ^ (sw << 3))] = vr[p][e];
            }
        }

        __syncthreads();    // K DMA drained + V ds_writes visible

        #pragma unroll
        for (int sub = 0; sub < 2; ++sub) {
            const int kcs = kc + 64 * sub;
            const int base_[2] = {q0 + 32 * w - kcs, q0 + 32 * w - kcs + 16};
            const bool skip0 = (base_[0] + 15) < 0, skip1 = (base_[1] + 15) < 0;
            if (skip0 && skip1) continue;   // wave-uniform; no barriers inside sub loop

            // ---- K A-frags from LDS (chunk-swizzled rows) ----
            bf16x8 kb[4][2];
            #pragma unroll
            for (int nj = 0; nj < 4; ++nj) {
                const int row = sub * 64 + nj * 16 + m;
                #pragma unroll
                for (int ks = 0; ks < 2; ++ks) {
                    const int c = (g + 4 * ks) ^ (row & 7);
                    kb[nj][ks] = *reinterpret_cast<const bf16x8*>(Ks + row * 64 + c * 8);
                }
            }
            // ---- S^T = K·Q^T : row(4g+r)=k, col(m)=q ----
            f32x4 acc[2][4] = {};
            __builtin_amdgcn_s_setprio(1);
            #pragma unroll
            for (int nj = 0; nj < 4; ++nj)
                #pragma unroll
                for (int ks = 0; ks < 2; ++ks) {
                    if (!skip0) acc[0][nj] = __builtin_amdgcn_mfma_f32_16x16x32_bf16(kb[nj][ks], qa[0][ks], acc[0][nj], 0, 0, 0);
                    if (!skip1) acc[1][nj] = __builtin_amdgcn_mfma_f32_16x16x32_bf16(kb[nj][ks], qa[1][ks], acc[1][nj], 0, 0, 0);
                }
            __builtin_amdgcn_s_setprio(0);

            // ---- in-register softmax (q = m per lane), defer-max ----
            bf16x8 pa[2][2];
            #pragma unroll
            for (int qs = 0; qs < 2; ++qs) {
                const bool skq = qs ? skip1 : skip0;
                if (skq) continue;                       // wave-uniform
                if (base_[qs] < 63) {                    // diagonal sub-tile: causal mask
                    #pragma unroll
                    for (int nj = 0; nj < 4; ++nj)
                        #pragma unroll
                        for (int r = 0; r < 4; ++r)
                            if (16 * nj + 4 * g + r - m > base_[qs]) acc[qs][nj][r] = -3e38f;
                }
                float tmax = -3e38f;
                #pragma unroll
                for (int nj = 0; nj < 4; ++nj)
                    #pragma unroll
                    for (int r = 0; r < 4; ++r) tmax = fmaxf(tmax, acc[qs][nj][r]);
                tmax = fmaxf(tmax, __shfl_xor(tmax, 16));
                tmax = fmaxf(tmax, __shfl_xor(tmax, 32));
                if (!__all(tmax <= mrow[qs] + 8.f)) {    // T13 defer-max
                    const float mn = fmaxf(mrow[qs], tmax);
                    const float corr = __expf(mrow[qs] - mn);
                    mrow[qs] = mn;
                    lrow[qs] *= corr;
                    float c4[4];
                    #pragma unroll
                    for (int r = 0; r < 4; ++r) c4[r] = __shfl(corr, 4 * g + r);
                    #pragma unroll
                    for (int dg = 0; dg < 4; ++dg)
                        #pragma unroll
                        for (int r = 0; r < 4; ++r) o[qs][dg][r] *= c4[r];
                }
                float ssum = 0.f;
                #pragma unroll
                for (int nj = 0; nj < 4; ++nj)
                    #pragma unroll
                    for (int r = 0; r < 4; ++r) {
                        const float p = __expf(acc[qs][nj][r] - mrow[qs]);
                        acc[qs][nj][r] = p;
                        ssum += p;
                    }
                ssum += __shfl_xor(ssum, 16);
                ssum += __shfl_xor(ssum, 32);
                lrow[qs] += ssum;
                // pack P A-frags: slot (g,e): e<4 -> acc[2ks][e] (k=32ks+4g+e), e>=4 -> acc[2ks+1][e-4]
                #pragma unroll
                for (int ks = 0; ks < 2; ++ks) {
                    u16x8 pk;
                    #pragma unroll
                    for (int r = 0; r < 4; ++r) {
                        pk[r]     = f2bf(acc[qs][2 * ks][r]);
                        pk[r + 4] = f2bf(acc[qs][2 * ks + 1][r]);
                    }
                    pa[qs][ks] = __builtin_bit_cast(bf16x8, pk);
                }
            }

            // ---- PV: O[q(4g+r)][d(m)] += P·V, V slots match pa's k-permutation ----
            __builtin_amdgcn_s_setprio(1);
            #pragma unroll
            for (int dg = 0; dg < 4; ++dg) {
                const int d = 16 * dg + m;
                const int sw = ((d & 7) ^ (d >> 3)) & 7;
                #pragma unroll
                for (int ks = 0; ks < 2; ++ks) {
                    const int sb = (32 * ks + 8 * g) ^ (sw << 3);
                    bf16x8 vb = *reinterpret_cast<const bf16x8*>(Vt + d * 128 + sub * 64 + sb);
                    if (!skip0) o[0][dg] = __builtin_amdgcn_mfma_f32_16x16x32_bf16(pa[0][ks], vb, o[0][dg], 0, 0, 0);
                    if (!skip1) o[1][dg] = __builtin_amdgcn_mfma_f32_16x16x32_bf16(pa[1][ks], vb, o[1][dg], 0, 0, 0);
                }
            }
            __builtin_amdgcn_s_setprio(0);
        }
    }

    // ---- epilogue: redistribute l (q=m lanes -> q=4g+r lanes), normalize, store ----
    #pragma unroll
    for (int qs = 0; qs < 2; ++qs) {
        float linv[4];
        #pragma unroll
        for (int r = 0; r < 4; ++r) linv[r] = 1.0f / __shfl(lrow[qs], 4 * g + r);
        #pragma unroll
        for (int dg = 0; dg < 4; ++dg)
            #pragma unroll
            for (int r = 0; r < 4; ++r) {
                const int row = q0 + 32 * w + 16 * qs + 4 * g + r;
                ctx[(bS + row) * DD + h * HDD + 16 * dg + m] = f2bf(o[qs][dg][r] * linv[r]);
            }
    }
}

extern "C" void kernel_launch(void* const* d_in, const int* in_sizes, int n_in,
                              void* d_out, int out_size, void* d_ws, size_t ws_size,
                              hipStream_t stream) {
    const float* x     = (const float*)d_in[0];
    const float* W_qkv = (const float*)d_in[1];
    const float* b_qkv = (const float*)d_in[2];
    const float* W_out = (const float*)d_in[3];
    const float* b_out = (const float*)d_in[4];

    u16* xb    = (u16*)d_ws;                                  // [8192][1024]
    u16* Wqkvt = xb    + (size_t)MTOT * DD;                   // [3072][1024]
    u16* Wot   = Wqkvt + (size_t)NQKV * DD;                   // [1024][1024]
    u16* qkv   = Wot   + (size_t)DD * DD;                     // [8192][3072]
    u16* ctx   = qkv   + (size_t)MTOT * NQKV;                 // [8192][1024]

    cvt_f32_bf16<<<(MTOT * DD) / 1024, 256, 0, stream>>>(x, xb, MTOT * DD);
    transpose_cvt<<<dim3(NQKV / 32, DD / 32), 256, 0, stream>>>(W_qkv, Wqkvt, DD, NQKV);
    transpose_cvt<<<dim3(DD / 32, DD / 32), 256, 0, stream>>>(W_out, Wot, DD, DD);
    gemm_bt<1, 1><<<(MTOT / 128) * (NQKV / 128), 256, 0, stream>>>(xb, Wqkvt, b_qkv, qkv, MTOT, NQKV, DD);
    attn_fwd5<<<dim3(SS / 128, HH, BB), 256, 0, stream>>>(qkv, ctx);
    gemm_bt<0, 0><<<(MTOT / 128) * (DD / 128), 256, 0, stream>>>(ctx, Wot, b_out, (float*)d_out, MTOT, DD, DD);
}